// Round 3
// baseline (156.330 us; speedup 1.0000x reference)
//
#include <hip/hip_runtime.h>

static constexpr int B = 16, C = 64, H = 256, W = 256;
static constexpr int HW = H * W;              // 65536
static constexpr int KS = 7, PAD = 3;
static constexpr int CH = 8;                  // images per chunk (128 MiB of x)

typedef float f4 __attribute__((ext_vector_type(4)));

// ---------------- Kernel 1: channel-wise mean & max (one batch chunk) -------
// One thread per 4 consecutive pixels. Loop over 64 channels, stride HW;
// fully coalesced 1 KiB per wave per instruction. Regular loads so the
// chunk of x lands in L3 for the fused kernel's re-read.
__global__ void __launch_bounds__(256) reduce_mean_max(
    const float* __restrict__ x, float* __restrict__ avg, float* __restrict__ mx,
    int b0)
{
    int idx = blockIdx.x * 256 + threadIdx.x;     // over CH*HW/4
    int b   = b0 + (idx >> 14);                   // HW/4 = 16384 = 2^14
    int p   = idx & (HW / 4 - 1);
    const f4* xp = reinterpret_cast<const f4*>(x) + (size_t)b * (C * (HW / 4)) + p;
    f4 v = xp[0];
    f4 s = v;
    f4 a = v;
    #pragma unroll 8
    for (int c = 1; c < C; ++c) {
        f4 t = xp[(size_t)c * (HW / 4)];
        s += t;
        a.x = fmaxf(a.x, t.x); a.y = fmaxf(a.y, t.y);
        a.z = fmaxf(a.z, t.z); a.w = fmaxf(a.w, t.w);
    }
    const float inv = 1.0f / C;
    size_t o = (size_t)b * (HW / 4) + p;
    reinterpret_cast<f4*>(avg)[o] = s * inv;
    reinterpret_cast<f4*>(mx)[o]  = a;
}

// ------- Kernel 2 (fused): 7x7 conv + bias + sigmoid + broadcast multiply ---
// Block = one image-row strip of 4 rows x 256 cols. Stage the 10x262 avg/max
// halo in LDS, conv->sigmoid->mask strip in LDS, then loop 64 channels
// multiplying x (L3-hot from kernel 1) and nt-storing out (never re-read,
// don't evict x).
__global__ void __launch_bounds__(256) conv_mul(
    const float* __restrict__ x, const float* __restrict__ avg,
    const float* __restrict__ mx, const float* __restrict__ wgt,
    const float* __restrict__ bias, float* __restrict__ out, int b0)
{
    __shared__ float sa[10][264];     // rows h0-3..h0+6, cols -3..258 at +3
    __shared__ float sm[10][264];
    __shared__ float smask[4][256];
    __shared__ float sw[2][49];
    __shared__ float sbias;

    const int t  = threadIdx.x;
    const int h0 = blockIdx.x * 4;
    const int b  = b0 + blockIdx.y;

    if (t < 98) ((float*)sw)[t] = wgt[t];
    if (t == 98) sbias = bias[0];

    const float* ap = avg + (size_t)b * HW;
    const float* mp = mx  + (size_t)b * HW;
    for (int e = t; e < 10 * 262; e += 256) {
        int r = e / 262, ci = e % 262;            // col = ci - 3
        int gh = h0 + r - PAD, gw = ci - PAD;
        bool ok = ((unsigned)gh < (unsigned)H) && ((unsigned)gw < (unsigned)W);
        int gi = gh * W + gw;
        sa[r][ci] = ok ? ap[gi] : 0.0f;
        sm[r][ci] = ok ? mp[gi] : 0.0f;
    }
    __syncthreads();

    // thread t computes mask for column t, rows 0..3 of the strip
    #pragma unroll
    for (int r = 0; r < 4; ++r) {
        float acc = sbias;
        #pragma unroll
        for (int ky = 0; ky < KS; ++ky) {
            #pragma unroll
            for (int kx = 0; kx < KS; ++kx) {
                acc += sa[r + ky][t + kx] * sw[0][ky * KS + kx];
                acc += sm[r + ky][t + kx] * sw[1][ky * KS + kx];
            }
        }
        smask[r][t] = 1.0f / (1.0f + expf(-acc));
    }
    __syncthreads();

    // multiply phase: wave = one row of the strip, contiguous 1 KiB per instr
    const int row = t >> 6;          // 0..3
    const int q   = t & 63;          // f4 index within the row
    f4 mv = reinterpret_cast<const f4*>(&smask[row][0])[q];
    size_t base = (((size_t)b * C) * H + (h0 + row)) * (W / 4) + q;   // f4 units
    const f4* xp = reinterpret_cast<const f4*>(x)   + base;
    f4*       op = reinterpret_cast<f4*>(out)       + base;
    #pragma unroll 8
    for (int c = 0; c < C; ++c) {
        f4 xv = xp[(size_t)c * (H * (W / 4))];
        __builtin_nontemporal_store(xv * mv, op + (size_t)c * (H * (W / 4)));
    }
}

extern "C" void kernel_launch(void* const* d_in, const int* in_sizes, int n_in,
                              void* d_out, int out_size, void* d_ws, size_t ws_size,
                              hipStream_t stream) {
    const float* x      = (const float*)d_in[0];
    const float* conv_w = (const float*)d_in[1];   // [1,2,7,7] OIHW flat
    const float* conv_b = (const float*)d_in[2];   // [1]
    float* out  = (float*)d_out;

    float* avg  = (float*)d_ws;                    // B*HW floats = 4 MiB
    float* mx   = avg + (size_t)B * HW;            // 4 MiB

    for (int chunk = 0; chunk < B / CH; ++chunk) {
        int b0 = chunk * CH;
        reduce_mean_max<<<(CH * HW / 4) / 256, 256, 0, stream>>>(x, avg, mx, b0);
        dim3 g(H / 4, CH);
        conv_mul<<<g, 256, 0, stream>>>(x, avg, mx, conv_w, conv_b, out, b0);
    }
}